// Round 7
// baseline (609.394 us; speedup 1.0000x reference)
//
#include <hip/hip_runtime.h>
#include <cstdint>
#include <cstddef>

#define BB 2
#define SS 2048
#define DD 1024
#define HH 16
#define DKK 64

typedef __attribute__((ext_vector_type(8))) short short8x;
typedef __attribute__((ext_vector_type(4))) float f32x4;

__device__ __forceinline__ unsigned short f2b(float f) {
  union { float f; unsigned u; } v; v.f = f;
  unsigned r = (v.u + 0x7fffu + ((v.u >> 16) & 1u)) >> 16;  // RNE
  return (unsigned short)r;
}

__device__ __forceinline__ f32x4 mfma16(short8x a, short8x b, f32x4 c) {
  return __builtin_amdgcn_mfma_f32_16x16x32_bf16(a, b, c, 0, 0, 0);
}

// Fragment-major Q/K layout (see R5): frag (bh,rb,ks) at ((bh*128+rb)*2+ks)*512 + lane*8.
// V^T frag (bh,rbv,kc) at ((bh*4+rbv)*64+kc)*512 + lane*8.
// R6: fixed m=0 (scores O(1)). R7: flash splits K range across 2 blocks (associative
// accumulation) -> 2048 blocks, grid no longer caps occupancy; partial fp32 ctx + l
// combined by a small kernel. Epilogue folded: arg = inv*fma(C1,r2,C2*a), exp2.
#define C1F 0.0225421076f  // (1/64)*log2e
#define C2F 0.0541010849f  // (0.3/8)*log2e

// ---------------- pack weights
__global__ void pack_w_kernel(const float* __restrict__ Wq_r, const float* __restrict__ Wq_i,
                              const float* __restrict__ Wk_r, const float* __restrict__ Wk_i,
                              const float* __restrict__ Wv, const float* __restrict__ Wo,
                              unsigned short* __restrict__ WcatT, unsigned short* __restrict__ WoT) {
  int gid = blockIdx.x * 256 + threadIdx.x;
  if (gid < 5120 * 2048) {
    int k = gid & 2047;
    int n = gid >> 11;
    int q = n >> 10, j = n & 1023;
    float v;
    if (k < 1024) {
      const float* src = (q == 0) ? Wq_r : (q == 1) ? Wq_i : (q == 2) ? Wk_r : (q == 3) ? Wk_i : Wv;
      v = src[k * 1024 + j];
    } else {
      int k2 = k - 1024;
      if (q == 0)      v = -Wq_i[k2 * 1024 + j];
      else if (q == 1) v =  Wq_r[k2 * 1024 + j];
      else if (q == 2) v = -Wk_i[k2 * 1024 + j];
      else if (q == 3) v =  Wk_r[k2 * 1024 + j];
      else             v = 0.0f;
    }
    WcatT[gid] = f2b(v);
  } else {
    int g2 = gid - 5120 * 2048;            // n*1024 + k
    int k = g2 & 1023, n = g2 >> 10;
    WoT[g2] = f2b(Wo[k * 1024 + n]);
  }
}

// ---------------- pack X: Xcat[4096][2048] = [z_real | z_imag] (bf16)
__global__ void pack_x_kernel(const float* __restrict__ zr, const float* __restrict__ zi,
                              unsigned short* __restrict__ X) {
  int gid = blockIdx.x * 256 + threadIdx.x;  // 4096*2048
  int k = gid & 2047, m = gid >> 11;
  float v = (k < 1024) ? zr[m * 1024 + k] : zi[m * 1024 + (k - 1024)];
  X[gid] = f2b(v);
}

// ---------------- projection GEMM: epilogue writes fragment-major Q/K and V^T
__global__ __launch_bounds__(256, 2) void gemm_proj_kernel(
    const unsigned short* __restrict__ A, const unsigned short* __restrict__ Bt,
    unsigned short* __restrict__ Qr, unsigned short* __restrict__ Qi,
    unsigned short* __restrict__ Kr, unsigned short* __restrict__ Ki,
    unsigned short* __restrict__ VT) {
  constexpr int K = 2048;
  __shared__ __attribute__((aligned(16))) unsigned short As[128][40];
  __shared__ __attribute__((aligned(16))) unsigned short Bs[128][40];
  const int tid = threadIdx.x;
  const int m0 = blockIdx.x * 128;
  const int n0 = blockIdx.y * 128;
  const int lane = tid & 63, wid = tid >> 6;
  const int l15 = lane & 15, quad = lane >> 4;
  const int wm = (wid & 1) * 64, wn = (wid >> 1) * 64;
  const int lrow = tid >> 1, lseg = (tid & 1) * 16;
  f32x4 acc[4][4] = {};
  const int4* ga = (const int4*)(A + (size_t)(m0 + lrow) * K + lseg);
  const int4* gb = (const int4*)(Bt + (size_t)(n0 + lrow) * K + lseg);
  for (int k0 = 0; k0 < K; k0 += 32) {
    int4 a0 = ga[0], a1 = ga[1];
    int4 b0 = gb[0], b1 = gb[1];
    __syncthreads();
    *(int4*)&As[lrow][lseg] = a0;  *(int4*)&As[lrow][lseg + 8] = a1;
    *(int4*)&Bs[lrow][lseg] = b0;  *(int4*)&Bs[lrow][lseg + 8] = b1;
    __syncthreads();
    short8x af[4], bfr[4];
#pragma unroll
    for (int i = 0; i < 4; i++) af[i]  = *(const short8x*)&As[wm + i * 16 + l15][quad * 8];
#pragma unroll
    for (int i = 0; i < 4; i++) bfr[i] = *(const short8x*)&Bs[wn + i * 16 + l15][quad * 8];
#pragma unroll
    for (int mi = 0; mi < 4; mi++)
#pragma unroll
      for (int ni = 0; ni < 4; ni++)
        acc[mi][ni] = mfma16(af[mi], bfr[ni], acc[mi][ni]);
    ga += 4; gb += 4;
  }
#pragma unroll
  for (int mi = 0; mi < 4; mi++) {
#pragma unroll
    for (int ni = 0; ni < 4; ni++) {
      int gn = n0 + wn + ni * 16 + l15;
      if (gn < 4096) {
        int which = gn >> 10, j = gn & 1023, h = j >> 6, dk = j & 63;
        int ks = dk >> 5, q = (dk >> 3) & 3, e = dk & 7;
        unsigned short* dst = (which == 0) ? Qr : (which == 1) ? Qi : (which == 2) ? Kr : Ki;
#pragma unroll
        for (int r = 0; r < 4; r++) {
          int gm = m0 + wm + mi * 16 + quad * 4 + r;
          int b = gm >> 11, s = gm & 2047;
          int bh = b * HH + h, rb = s >> 4, l = s & 15;
          dst[(size_t)(((bh * 128 + rb) * 2 + ks) * 512 + (q * 16 + l) * 8 + e)] = f2b(acc[mi][ni][r]);
        }
      } else {
        int j = gn - 4096, h = j >> 6, dk = j & 63;
        int rbv = dk >> 4, lv = dk & 15;
#pragma unroll
        for (int r = 0; r < 4; r++) {
          int gm = m0 + wm + mi * 16 + quad * 4 + r;
          int b = gm >> 11, s = gm & 2047;
          int bh = b * HH + h, kc = s >> 5, qv = (s >> 3) & 3, ev = s & 7;
          VT[(size_t)(((bh * 4 + rbv) * 64 + kc) * 512 + (qv * 16 + lv) * 8 + ev)] = f2b(acc[mi][ni][r]);
        }
      }
    }
  }
}

// ---------------- flash attention, fixed-m, K-range split: block = (qtile32idx, h, b*2+half).
// Each block does 1024 K columns; writes UNNORMALIZED fp32 partial ctx + partial l.
__global__ __launch_bounds__(256, 6) void flash_kernel(
    const unsigned short* __restrict__ Qr, const unsigned short* __restrict__ Qi,
    const unsigned short* __restrict__ Kr, const unsigned short* __restrict__ Ki,
    const unsigned short* __restrict__ VT, const int* __restrict__ mask,
    float* __restrict__ ctxP0, float* __restrict__ ctxP1,
    float* __restrict__ Lp0, float* __restrict__ Lp1) {
  __shared__ __attribute__((aligned(16))) unsigned short Ps[4][16][72];
  const int tid = threadIdx.x;
  const int lane = tid & 63, wid = tid >> 6;
  const int l15 = lane & 15, quad = lane >> 4;
  const int qt = blockIdx.x * 64;
  const int h = blockIdx.y;
  const int b = blockIdx.z >> 1, half = blockIdx.z & 1;
  const int bh = b * HH + h;
  float* __restrict__ cp = half ? ctxP1 : ctxP0;
  float* __restrict__ lp = half ? Lp1 : Lp0;
  const int rb = (qt >> 4) + wid;
  const int qbase = (bh * 128 + rb) * 1024 + lane * 8;
  short8x fqr0 = *(const short8x*)(Qr + qbase);
  short8x fqr1 = *(const short8x*)(Qr + qbase + 512);
  short8x fqi0 = *(const short8x*)(Qi + qbase);
  short8x fqi1 = *(const short8x*)(Qi + qbase + 512);
  f32x4 ctxacc[4] = {};
  float lsum[4] = {0.f, 0.f, 0.f, 0.f};

  const int kt0 = half * 1024;
  for (int kt = kt0; kt < kt0 + 1024; kt += 64) {
#pragma unroll
    for (int nb = 0; nb < 4; nb++) {
      float mkf = (float)mask[b * SS + kt + nb * 16 + l15];
      const int koff = (bh * 128 + (kt >> 4) + nb) * 1024 + lane * 8;
      short8x bkr0 = *(const short8x*)(Kr + koff);
      short8x bkr1 = *(const short8x*)(Kr + koff + 512);
      short8x bki0 = *(const short8x*)(Ki + koff);
      short8x bki1 = *(const short8x*)(Ki + koff + 512);
      f32x4 sr = {0.f, 0.f, 0.f, 0.f};
      sr = mfma16(fqr0, bkr0, sr);  sr = mfma16(fqr1, bkr1, sr);
      sr = mfma16(fqi0, bki0, sr);  sr = mfma16(fqi1, bki1, sr);
      f32x4 sa = {0.f, 0.f, 0.f, 0.f};
      sa = mfma16(fqi0, bkr0, sa);  sa = mfma16(fqi1, bkr1, sa);
      f32x4 sb = {0.f, 0.f, 0.f, 0.f};
      sb = mfma16(fqr0, bki0, sb);  sb = mfma16(fqr1, bki1, sb);
#pragma unroll
      for (int r = 0; r < 4; r++) {
        float a = sr[r];
        float d = sa[r] - sb[r];
        float r2 = __builtin_fmaf(a, a, d * d);
        float inv = rsqrtf(r2);
        float arg = inv * __builtin_fmaf(C1F, r2, C2F * a);
        float p = mkf * __builtin_exp2f(arg);
        lsum[r] += p;
        Ps[wid][quad * 4 + r][nb * 16 + l15] = f2b(p);
      }
    }
    // PV (Ps per-wave; lgkmcnt wait suffices, no barrier)
#pragma unroll
    for (int ks = 0; ks < 2; ks++)
#pragma unroll
      for (int db = 0; db < 4; db++) {
        int voff = ((bh * 4 + db) * 64 + (kt >> 5) + ks) * 512 + lane * 8;
        short8x bv = *(const short8x*)(VT + voff);
        short8x ap = *(const short8x*)&Ps[wid][l15][ks * 32 + quad * 8];
        ctxacc[db] = mfma16(ap, bv, ctxacc[db]);
      }
  }
  // reduce partial l over the 16 column-lanes
#pragma unroll
  for (int r = 0; r < 4; r++) {
#pragma unroll
    for (int off = 1; off < 16; off <<= 1) lsum[r] += __shfl_xor(lsum[r], off, 64);
  }
#pragma unroll
  for (int r = 0; r < 4; r++) {
    int s = qt + wid * 16 + quad * 4 + r;
#pragma unroll
    for (int db = 0; db < 4; db++)
      cp[((size_t)b * SS + s) * DD + h * DKK + db * 16 + l15] = ctxacc[db][r];
    if (l15 == 0) lp[(size_t)bh * SS + s] = lsum[r];
  }
}

// ---------------- combine: ctx_bf16 = (P0+P1) / (L0+L1)
__global__ __launch_bounds__(256) void combine_kernel(
    const float* __restrict__ ctxP0, const float* __restrict__ ctxP1,
    const float* __restrict__ Lp0, const float* __restrict__ Lp1,
    unsigned short* __restrict__ ctx) {
  int idx = blockIdx.x * 256 + threadIdx.x;   // 1048576 threads
  int g = idx * 4;
  int c = g & 1023, s = (g >> 10) & 2047, b = g >> 21;
  int h = c >> 6;
  size_t loff = (size_t)(b * HH + h) * SS + s;
  float linv = 1.0f / (Lp0[loff] + Lp1[loff]);
  float4 p0 = *(const float4*)(ctxP0 + g);
  float4 p1 = *(const float4*)(ctxP1 + g);
  ushort4 o;
  o.x = f2b((p0.x + p1.x) * linv);
  o.y = f2b((p0.y + p1.y) * linv);
  o.z = f2b((p0.z + p1.z) * linv);
  o.w = f2b((p0.w + p1.w) * linv);
  *(ushort4*)(ctx + g) = o;
}

// ---------------- output GEMM: out = ctx @ WoT^T + bias (unchanged)
__global__ __launch_bounds__(256, 2) void gemm_out_kernel(
    const unsigned short* __restrict__ A, const unsigned short* __restrict__ Bt,
    const float* __restrict__ bias, float* __restrict__ out) {
  constexpr int K = 1024;
  __shared__ __attribute__((aligned(16))) unsigned short As[128][40];
  __shared__ __attribute__((aligned(16))) unsigned short Bs[128][40];
  const int tid = threadIdx.x;
  const int m0 = blockIdx.x * 128;
  const int n0 = blockIdx.y * 128;
  const int lane = tid & 63, wid = tid >> 6;
  const int l15 = lane & 15, quad = lane >> 4;
  const int wm = (wid & 1) * 64, wn = (wid >> 1) * 64;
  const int lrow = tid >> 1, lseg = (tid & 1) * 16;
  f32x4 acc[4][4] = {};
  const int4* ga = (const int4*)(A + (size_t)(m0 + lrow) * K + lseg);
  const int4* gb = (const int4*)(Bt + (size_t)(n0 + lrow) * K + lseg);
  for (int k0 = 0; k0 < K; k0 += 32) {
    int4 a0 = ga[0], a1 = ga[1];
    int4 b0 = gb[0], b1 = gb[1];
    __syncthreads();
    *(int4*)&As[lrow][lseg] = a0;  *(int4*)&As[lrow][lseg + 8] = a1;
    *(int4*)&Bs[lrow][lseg] = b0;  *(int4*)&Bs[lrow][lseg + 8] = b1;
    __syncthreads();
    short8x af[4], bfr[4];
#pragma unroll
    for (int i = 0; i < 4; i++) af[i]  = *(const short8x*)&As[wm + i * 16 + l15][quad * 8];
#pragma unroll
    for (int i = 0; i < 4; i++) bfr[i] = *(const short8x*)&Bs[wn + i * 16 + l15][quad * 8];
#pragma unroll
    for (int mi = 0; mi < 4; mi++)
#pragma unroll
      for (int ni = 0; ni < 4; ni++)
        acc[mi][ni] = mfma16(af[mi], bfr[ni], acc[mi][ni]);
    ga += 4; gb += 4;
  }
#pragma unroll
  for (int mi = 0; mi < 4; mi++)
#pragma unroll
    for (int ni = 0; ni < 4; ni++) {
      int gn = n0 + wn + ni * 16 + l15;
      float bv = bias[gn];
#pragma unroll
      for (int r = 0; r < 4; r++) {
        int gm = m0 + wm + mi * 16 + quad * 4 + r;
        out[(size_t)gm * 1024 + gn] = acc[mi][ni][r] + bv;
      }
    }
}

// ---------------- probs_mean: fragment-major loads, fixed m=0, l = L0+L1, folded epilogue
__global__ __launch_bounds__(256, 3) void probsmean_kernel(
    const unsigned short* __restrict__ Qr, const unsigned short* __restrict__ Qi,
    const unsigned short* __restrict__ Kr, const unsigned short* __restrict__ Ki,
    const int* __restrict__ mask, const float* __restrict__ Lp0, const float* __restrict__ Lp1,
    float* __restrict__ out2) {
  const int tid = threadIdx.x, lane = tid & 63, wid = tid >> 6;
  const int l15 = lane & 15, quad = lane >> 4;
  const int qt = blockIdx.x * 64;
  const int kt = blockIdx.y * 64;
  const int b = blockIdx.z;
  const int qrow0 = qt + wid * 16;
  const int qrb = (qt >> 4) + wid;
  const int ktb = kt >> 4;
  float mkf[4];
#pragma unroll
  for (int nb = 0; nb < 4; nb++) mkf[nb] = (float)mask[b * SS + kt + nb * 16 + l15];
  float psum[4][4] = {};  // [nb][r]
  for (int h = 0; h < HH; h++) {
    const int bh = b * HH + h;
    const int qoff = (bh * 128 + qrb) * 1024 + lane * 8;
    short8x fqr0 = *(const short8x*)(Qr + qoff);
    short8x fqr1 = *(const short8x*)(Qr + qoff + 512);
    short8x fqi0 = *(const short8x*)(Qi + qoff);
    short8x fqi1 = *(const short8x*)(Qi + qoff + 512);
    const float4 lv0 = *(const float4*)(Lp0 + (size_t)bh * SS + qrow0 + quad * 4);
    const float4 lv1 = *(const float4*)(Lp1 + (size_t)bh * SS + qrow0 + quad * 4);
    float li[4];
    li[0] = 1.0f / (lv0.x + lv1.x); li[1] = 1.0f / (lv0.y + lv1.y);
    li[2] = 1.0f / (lv0.z + lv1.z); li[3] = 1.0f / (lv0.w + lv1.w);
#pragma unroll
    for (int nb = 0; nb < 4; nb++) {
      const int koff = (bh * 128 + ktb + nb) * 1024 + lane * 8;
      short8x bkr0 = *(const short8x*)(Kr + koff);
      short8x bkr1 = *(const short8x*)(Kr + koff + 512);
      short8x bki0 = *(const short8x*)(Ki + koff);
      short8x bki1 = *(const short8x*)(Ki + koff + 512);
      f32x4 sr = {0.f, 0.f, 0.f, 0.f};
      sr = mfma16(fqr0, bkr0, sr);  sr = mfma16(fqr1, bkr1, sr);
      sr = mfma16(fqi0, bki0, sr);  sr = mfma16(fqi1, bki1, sr);
      f32x4 sa = {0.f, 0.f, 0.f, 0.f};  // Qi.Kr
      sa = mfma16(fqi0, bkr0, sa);  sa = mfma16(fqi1, bkr1, sa);
      f32x4 sb = {0.f, 0.f, 0.f, 0.f};  // Qr.Ki
      sb = mfma16(fqr0, bki0, sb);  sb = mfma16(fqr1, bki1, sb);
#pragma unroll
      for (int r = 0; r < 4; r++) {
        float a = sr[r];
        float d = sa[r] - sb[r];
        float r2 = __builtin_fmaf(a, a, d * d);
        float inv = rsqrtf(r2);
        float arg = inv * __builtin_fmaf(C1F, r2, C2F * a);
        float p = mkf[nb] * __builtin_exp2f(arg) * li[r];
        psum[nb][r] += p;
      }
    }
  }
#pragma unroll
  for (int nb = 0; nb < 4; nb++)
#pragma unroll
    for (int r = 0; r < 4; r++) {
      int qrow = qrow0 + quad * 4 + r;
      out2[((size_t)b * SS + qrow) * SS + kt + nb * 16 + l15] = psum[nb][r] * 0.0625f;
    }
}

extern "C" void kernel_launch(void* const* d_in, const int* in_sizes, int n_in,
                              void* d_out, int out_size, void* d_ws, size_t ws_size,
                              hipStream_t stream) {
  const float* z_real = (const float*)d_in[0];
  const float* z_imag = (const float*)d_in[1];
  const float* Wq_r = (const float*)d_in[2];
  const float* Wq_i = (const float*)d_in[3];
  const float* Wk_r = (const float*)d_in[4];
  const float* Wk_i = (const float*)d_in[5];
  const float* Wv   = (const float*)d_in[6];
  const float* Wo_w = (const float*)d_in[7];
  const float* Wo_b = (const float*)d_in[8];
  const int*   mask = (const int*)d_in[9];
  char* ws = (char*)d_ws;

  // ws layout (bytes). ctxP0/ctxP1 ALIAS WcatT/Xcat: dead after gemm_proj (stream-serial).
  constexpr size_t QKV_BYTES = 8388608;  // B*H*S*DK*2
  unsigned short* Qr   = (unsigned short*)(ws + 0);
  unsigned short* Qi   = (unsigned short*)(ws + QKV_BYTES);
  unsigned short* Kr   = (unsigned short*)(ws + 2 * QKV_BYTES);
  unsigned short* Ki   = (unsigned short*)(ws + 3 * QKV_BYTES);
  unsigned short* VT   = (unsigned short*)(ws + 4 * QKV_BYTES);
  unsigned short* ctx  = (unsigned short*)(ws + 5 * QKV_BYTES);              // 8 MB bf16
  unsigned short* WcatT= (unsigned short*)(ws + 50331648);                   // 20 MB
  unsigned short* WoT  = (unsigned short*)(ws + 71303168);                   // 2 MB
  unsigned short* Xcat = (unsigned short*)(ws + 73400320);                   // 16 MB
  float* ctxP0 = (float*)(ws + 50331648);                                    // aliases WcatT (16 MB)
  float* ctxP1 = (float*)(ws + 73400320);                                    // aliases Xcat (16 MB)
  float* Lp0   = (float*)(ws + 90177536);                                    // 256 KB
  float* Lp1   = (float*)(ws + 90439680);                                    // 256 KB

  float* out  = (float*)d_out;
  float* out2 = out + (size_t)BB * SS * DD;

  pack_w_kernel<<<dim3(45056), dim3(256), 0, stream>>>(Wq_r, Wq_i, Wk_r, Wk_i, Wv, Wo_w, WcatT, WoT);
  pack_x_kernel<<<dim3(32768), dim3(256), 0, stream>>>(z_real, z_imag, Xcat);
  gemm_proj_kernel<<<dim3(32, 40), dim3(256), 0, stream>>>(Xcat, WcatT, Qr, Qi, Kr, Ki, VT);
  flash_kernel<<<dim3(32, 16, 4), dim3(256), 0, stream>>>(Qr, Qi, Kr, Ki, VT, mask, ctxP0, ctxP1, Lp0, Lp1);
  combine_kernel<<<dim3(4096), dim3(256), 0, stream>>>(ctxP0, ctxP1, Lp0, Lp1, ctx);
  gemm_out_kernel<<<dim3(32, 8), dim3(256), 0, stream>>>(ctx, WoT, Wo_b, out);
  probsmean_kernel<<<dim3(32, 32, 2), dim3(256), 0, stream>>>(Qr, Qi, Kr, Ki, mask, Lp0, Lp1, out2);
}

// Round 8
// 576.907 us; speedup vs baseline: 1.0563x; 1.0563x over previous
//
#include <hip/hip_runtime.h>
#include <cstdint>
#include <cstddef>

#define BB 2
#define SS 2048
#define DD 1024
#define HH 16
#define DKK 64

typedef __attribute__((ext_vector_type(8))) short short8x;
typedef __attribute__((ext_vector_type(4))) float f32x4;

__device__ __forceinline__ unsigned short f2b(float f) {
  union { float f; unsigned u; } v; v.f = f;
  unsigned r = (v.u + 0x7fffu + ((v.u >> 16) & 1u)) >> 16;  // RNE
  return (unsigned short)r;
}

// hot-path bf16: round-half-up, 2 VALU (vs ~5 for RNE). Used only for Ps probabilities.
__device__ __forceinline__ unsigned short f2b_fast(float f) {
  union { float f; unsigned u; } v; v.f = f;
  return (unsigned short)((v.u + 0x8000u) >> 16);
}

__device__ __forceinline__ f32x4 mfma16(short8x a, short8x b, f32x4 c) {
  return __builtin_amdgcn_mfma_f32_16x16x32_bf16(a, b, c, 0, 0, 0);
}

// Fragment-major Q/K layout (R5): frag (bh,rb,ks) at ((bh*128+rb)*2+ks)*512 + lane*8.
// V^T frag (bh,rbv,kc) at ((bh*4+rbv)*64+kc)*512 + lane*8.
// R6: fixed m=0. R7: K-split across 2 blocks + combine. R8: raw-HW transcendentals —
// rocprof showed ~62 VALU lane-ops/score-element; rsqrtf/__builtin_exp2f lower to
// multi-inst OCML routines. v_rsq_f32 + v_exp_f32 directly (~1 ulp, margin 3.3x).
#define C1F 0.0225421076f  // (1/64)*log2e
#define C2F 0.0541010849f  // (0.3/8)*log2e

// ---------------- pack weights
__global__ void pack_w_kernel(const float* __restrict__ Wq_r, const float* __restrict__ Wq_i,
                              const float* __restrict__ Wk_r, const float* __restrict__ Wk_i,
                              const float* __restrict__ Wv, const float* __restrict__ Wo,
                              unsigned short* __restrict__ WcatT, unsigned short* __restrict__ WoT) {
  int gid = blockIdx.x * 256 + threadIdx.x;
  if (gid < 5120 * 2048) {
    int k = gid & 2047;
    int n = gid >> 11;
    int q = n >> 10, j = n & 1023;
    float v;
    if (k < 1024) {
      const float* src = (q == 0) ? Wq_r : (q == 1) ? Wq_i : (q == 2) ? Wk_r : (q == 3) ? Wk_i : Wv;
      v = src[k * 1024 + j];
    } else {
      int k2 = k - 1024;
      if (q == 0)      v = -Wq_i[k2 * 1024 + j];
      else if (q == 1) v =  Wq_r[k2 * 1024 + j];
      else if (q == 2) v = -Wk_i[k2 * 1024 + j];
      else if (q == 3) v =  Wk_r[k2 * 1024 + j];
      else             v = 0.0f;
    }
    WcatT[gid] = f2b(v);
  } else {
    int g2 = gid - 5120 * 2048;            // n*1024 + k
    int k = g2 & 1023, n = g2 >> 10;
    WoT[g2] = f2b(Wo[k * 1024 + n]);
  }
}

// ---------------- pack X: Xcat[4096][2048] = [z_real | z_imag] (bf16)
__global__ void pack_x_kernel(const float* __restrict__ zr, const float* __restrict__ zi,
                              unsigned short* __restrict__ X) {
  int gid = blockIdx.x * 256 + threadIdx.x;  // 4096*2048
  int k = gid & 2047, m = gid >> 11;
  float v = (k < 1024) ? zr[m * 1024 + k] : zi[m * 1024 + (k - 1024)];
  X[gid] = f2b(v);
}

// ---------------- projection GEMM: epilogue writes fragment-major Q/K and V^T
__global__ __launch_bounds__(256, 2) void gemm_proj_kernel(
    const unsigned short* __restrict__ A, const unsigned short* __restrict__ Bt,
    unsigned short* __restrict__ Qr, unsigned short* __restrict__ Qi,
    unsigned short* __restrict__ Kr, unsigned short* __restrict__ Ki,
    unsigned short* __restrict__ VT) {
  constexpr int K = 2048;
  __shared__ __attribute__((aligned(16))) unsigned short As[128][40];
  __shared__ __attribute__((aligned(16))) unsigned short Bs[128][40];
  const int tid = threadIdx.x;
  const int m0 = blockIdx.x * 128;
  const int n0 = blockIdx.y * 128;
  const int lane = tid & 63, wid = tid >> 6;
  const int l15 = lane & 15, quad = lane >> 4;
  const int wm = (wid & 1) * 64, wn = (wid >> 1) * 64;
  const int lrow = tid >> 1, lseg = (tid & 1) * 16;
  f32x4 acc[4][4] = {};
  const int4* ga = (const int4*)(A + (size_t)(m0 + lrow) * K + lseg);
  const int4* gb = (const int4*)(Bt + (size_t)(n0 + lrow) * K + lseg);
  for (int k0 = 0; k0 < K; k0 += 32) {
    int4 a0 = ga[0], a1 = ga[1];
    int4 b0 = gb[0], b1 = gb[1];
    __syncthreads();
    *(int4*)&As[lrow][lseg] = a0;  *(int4*)&As[lrow][lseg + 8] = a1;
    *(int4*)&Bs[lrow][lseg] = b0;  *(int4*)&Bs[lrow][lseg + 8] = b1;
    __syncthreads();
    short8x af[4], bfr[4];
#pragma unroll
    for (int i = 0; i < 4; i++) af[i]  = *(const short8x*)&As[wm + i * 16 + l15][quad * 8];
#pragma unroll
    for (int i = 0; i < 4; i++) bfr[i] = *(const short8x*)&Bs[wn + i * 16 + l15][quad * 8];
#pragma unroll
    for (int mi = 0; mi < 4; mi++)
#pragma unroll
      for (int ni = 0; ni < 4; ni++)
        acc[mi][ni] = mfma16(af[mi], bfr[ni], acc[mi][ni]);
    ga += 4; gb += 4;
  }
#pragma unroll
  for (int mi = 0; mi < 4; mi++) {
#pragma unroll
    for (int ni = 0; ni < 4; ni++) {
      int gn = n0 + wn + ni * 16 + l15;
      if (gn < 4096) {
        int which = gn >> 10, j = gn & 1023, h = j >> 6, dk = j & 63;
        int ks = dk >> 5, q = (dk >> 3) & 3, e = dk & 7;
        unsigned short* dst = (which == 0) ? Qr : (which == 1) ? Qi : (which == 2) ? Kr : Ki;
#pragma unroll
        for (int r = 0; r < 4; r++) {
          int gm = m0 + wm + mi * 16 + quad * 4 + r;
          int b = gm >> 11, s = gm & 2047;
          int bh = b * HH + h, rb = s >> 4, l = s & 15;
          dst[(size_t)(((bh * 128 + rb) * 2 + ks) * 512 + (q * 16 + l) * 8 + e)] = f2b(acc[mi][ni][r]);
        }
      } else {
        int j = gn - 4096, h = j >> 6, dk = j & 63;
        int rbv = dk >> 4, lv = dk & 15;
#pragma unroll
        for (int r = 0; r < 4; r++) {
          int gm = m0 + wm + mi * 16 + quad * 4 + r;
          int b = gm >> 11, s = gm & 2047;
          int bh = b * HH + h, kc = s >> 5, qv = (s >> 3) & 3, ev = s & 7;
          VT[(size_t)(((bh * 4 + rbv) * 64 + kc) * 512 + (qv * 16 + lv) * 8 + ev)] = f2b(acc[mi][ni][r]);
        }
      }
    }
  }
}

// ---------------- flash attention, fixed-m, K-range split, raw-HW transcendentals
__global__ __launch_bounds__(256, 6) void flash_kernel(
    const unsigned short* __restrict__ Qr, const unsigned short* __restrict__ Qi,
    const unsigned short* __restrict__ Kr, const unsigned short* __restrict__ Ki,
    const unsigned short* __restrict__ VT, const int* __restrict__ mask,
    float* __restrict__ ctxP0, float* __restrict__ ctxP1,
    float* __restrict__ Lp0, float* __restrict__ Lp1) {
  __shared__ __attribute__((aligned(16))) unsigned short Ps[4][16][72];
  const int tid = threadIdx.x;
  const int lane = tid & 63, wid = tid >> 6;
  const int l15 = lane & 15, quad = lane >> 4;
  const int qt = blockIdx.x * 64;
  const int h = blockIdx.y;
  const int b = blockIdx.z >> 1, half = blockIdx.z & 1;
  const int bh = b * HH + h;
  float* __restrict__ cp = half ? ctxP1 : ctxP0;
  float* __restrict__ lp = half ? Lp1 : Lp0;
  const int rb = (qt >> 4) + wid;
  const int qbase = (bh * 128 + rb) * 1024 + lane * 8;
  short8x fqr0 = *(const short8x*)(Qr + qbase);
  short8x fqr1 = *(const short8x*)(Qr + qbase + 512);
  short8x fqi0 = *(const short8x*)(Qi + qbase);
  short8x fqi1 = *(const short8x*)(Qi + qbase + 512);
  f32x4 ctxacc[4] = {};
  float lsum[4] = {0.f, 0.f, 0.f, 0.f};

  const int kt0 = half * 1024;
  for (int kt = kt0; kt < kt0 + 1024; kt += 64) {
#pragma unroll
    for (int nb = 0; nb < 4; nb++) {
      float mkf = (float)mask[b * SS + kt + nb * 16 + l15];
      const int koff = (bh * 128 + (kt >> 4) + nb) * 1024 + lane * 8;
      short8x bkr0 = *(const short8x*)(Kr + koff);
      short8x bkr1 = *(const short8x*)(Kr + koff + 512);
      short8x bki0 = *(const short8x*)(Ki + koff);
      short8x bki1 = *(const short8x*)(Ki + koff + 512);
      f32x4 sr = {0.f, 0.f, 0.f, 0.f};
      sr = mfma16(fqr0, bkr0, sr);  sr = mfma16(fqr1, bkr1, sr);
      sr = mfma16(fqi0, bki0, sr);  sr = mfma16(fqi1, bki1, sr);
      f32x4 sa = {0.f, 0.f, 0.f, 0.f};
      sa = mfma16(fqi0, bkr0, sa);  sa = mfma16(fqi1, bkr1, sa);
      f32x4 sb = {0.f, 0.f, 0.f, 0.f};
      sb = mfma16(fqr0, bki0, sb);  sb = mfma16(fqr1, bki1, sb);
#pragma unroll
      for (int r = 0; r < 4; r++) {
        float a = sr[r];
        float d = sa[r] - sb[r];
        float r2 = __builtin_fmaf(a, a, d * d);
        float inv = __builtin_amdgcn_rsqf(r2);
        float arg = inv * __builtin_fmaf(C1F, r2, C2F * a);
        float p = mkf * __builtin_amdgcn_exp2f(arg);
        lsum[r] += p;
        Ps[wid][quad * 4 + r][nb * 16 + l15] = f2b_fast(p);
      }
    }
    // PV (Ps per-wave; lgkmcnt wait suffices, no barrier)
#pragma unroll
    for (int ks = 0; ks < 2; ks++)
#pragma unroll
      for (int db = 0; db < 4; db++) {
        int voff = ((bh * 4 + db) * 64 + (kt >> 5) + ks) * 512 + lane * 8;
        short8x bv = *(const short8x*)(VT + voff);
        short8x ap = *(const short8x*)&Ps[wid][l15][ks * 32 + quad * 8];
        ctxacc[db] = mfma16(ap, bv, ctxacc[db]);
      }
  }
  // reduce partial l over the 16 column-lanes
#pragma unroll
  for (int r = 0; r < 4; r++) {
#pragma unroll
    for (int off = 1; off < 16; off <<= 1) lsum[r] += __shfl_xor(lsum[r], off, 64);
  }
#pragma unroll
  for (int r = 0; r < 4; r++) {
    int s = qt + wid * 16 + quad * 4 + r;
#pragma unroll
    for (int db = 0; db < 4; db++)
      cp[((size_t)b * SS + s) * DD + h * DKK + db * 16 + l15] = ctxacc[db][r];
    if (l15 == 0) lp[(size_t)bh * SS + s] = lsum[r];
  }
}

// ---------------- combine: ctx_bf16 = (P0+P1) / (L0+L1)
__global__ __launch_bounds__(256) void combine_kernel(
    const float* __restrict__ ctxP0, const float* __restrict__ ctxP1,
    const float* __restrict__ Lp0, const float* __restrict__ Lp1,
    unsigned short* __restrict__ ctx) {
  int idx = blockIdx.x * 256 + threadIdx.x;   // 1048576 threads
  int g = idx * 4;
  int c = g & 1023, s = (g >> 10) & 2047, b = g >> 21;
  int h = c >> 6;
  size_t loff = (size_t)(b * HH + h) * SS + s;
  float linv = 1.0f / (Lp0[loff] + Lp1[loff]);
  float4 p0 = *(const float4*)(ctxP0 + g);
  float4 p1 = *(const float4*)(ctxP1 + g);
  ushort4 o;
  o.x = f2b((p0.x + p1.x) * linv);
  o.y = f2b((p0.y + p1.y) * linv);
  o.z = f2b((p0.z + p1.z) * linv);
  o.w = f2b((p0.w + p1.w) * linv);
  *(ushort4*)(ctx + g) = o;
}

// ---------------- output GEMM: out = ctx @ WoT^T + bias (unchanged)
__global__ __launch_bounds__(256, 2) void gemm_out_kernel(
    const unsigned short* __restrict__ A, const unsigned short* __restrict__ Bt,
    const float* __restrict__ bias, float* __restrict__ out) {
  constexpr int K = 1024;
  __shared__ __attribute__((aligned(16))) unsigned short As[128][40];
  __shared__ __attribute__((aligned(16))) unsigned short Bs[128][40];
  const int tid = threadIdx.x;
  const int m0 = blockIdx.x * 128;
  const int n0 = blockIdx.y * 128;
  const int lane = tid & 63, wid = tid >> 6;
  const int l15 = lane & 15, quad = lane >> 4;
  const int wm = (wid & 1) * 64, wn = (wid >> 1) * 64;
  const int lrow = tid >> 1, lseg = (tid & 1) * 16;
  f32x4 acc[4][4] = {};
  const int4* ga = (const int4*)(A + (size_t)(m0 + lrow) * K + lseg);
  const int4* gb = (const int4*)(Bt + (size_t)(n0 + lrow) * K + lseg);
  for (int k0 = 0; k0 < K; k0 += 32) {
    int4 a0 = ga[0], a1 = ga[1];
    int4 b0 = gb[0], b1 = gb[1];
    __syncthreads();
    *(int4*)&As[lrow][lseg] = a0;  *(int4*)&As[lrow][lseg + 8] = a1;
    *(int4*)&Bs[lrow][lseg] = b0;  *(int4*)&Bs[lrow][lseg + 8] = b1;
    __syncthreads();
    short8x af[4], bfr[4];
#pragma unroll
    for (int i = 0; i < 4; i++) af[i]  = *(const short8x*)&As[wm + i * 16 + l15][quad * 8];
#pragma unroll
    for (int i = 0; i < 4; i++) bfr[i] = *(const short8x*)&Bs[wn + i * 16 + l15][quad * 8];
#pragma unroll
    for (int mi = 0; mi < 4; mi++)
#pragma unroll
      for (int ni = 0; ni < 4; ni++)
        acc[mi][ni] = mfma16(af[mi], bfr[ni], acc[mi][ni]);
    ga += 4; gb += 4;
  }
#pragma unroll
  for (int mi = 0; mi < 4; mi++)
#pragma unroll
    for (int ni = 0; ni < 4; ni++) {
      int gn = n0 + wn + ni * 16 + l15;
      float bv = bias[gn];
#pragma unroll
      for (int r = 0; r < 4; r++) {
        int gm = m0 + wm + mi * 16 + quad * 4 + r;
        out[(size_t)gm * 1024 + gn] = acc[mi][ni][r] + bv;
      }
    }
}

// ---------------- probs_mean: fragment-major, fixed m=0, raw-HW transcendentals
__global__ __launch_bounds__(256, 3) void probsmean_kernel(
    const unsigned short* __restrict__ Qr, const unsigned short* __restrict__ Qi,
    const unsigned short* __restrict__ Kr, const unsigned short* __restrict__ Ki,
    const int* __restrict__ mask, const float* __restrict__ Lp0, const float* __restrict__ Lp1,
    float* __restrict__ out2) {
  const int tid = threadIdx.x, lane = tid & 63, wid = tid >> 6;
  const int l15 = lane & 15, quad = lane >> 4;
  const int qt = blockIdx.x * 64;
  const int kt = blockIdx.y * 64;
  const int b = blockIdx.z;
  const int qrow0 = qt + wid * 16;
  const int qrb = (qt >> 4) + wid;
  const int ktb = kt >> 4;
  float mkf[4];
#pragma unroll
  for (int nb = 0; nb < 4; nb++) mkf[nb] = (float)mask[b * SS + kt + nb * 16 + l15];
  float psum[4][4] = {};  // [nb][r]
  for (int h = 0; h < HH; h++) {
    const int bh = b * HH + h;
    const int qoff = (bh * 128 + qrb) * 1024 + lane * 8;
    short8x fqr0 = *(const short8x*)(Qr + qoff);
    short8x fqr1 = *(const short8x*)(Qr + qoff + 512);
    short8x fqi0 = *(const short8x*)(Qi + qoff);
    short8x fqi1 = *(const short8x*)(Qi + qoff + 512);
    const float4 lv0 = *(const float4*)(Lp0 + (size_t)bh * SS + qrow0 + quad * 4);
    const float4 lv1 = *(const float4*)(Lp1 + (size_t)bh * SS + qrow0 + quad * 4);
    float li[4];
    li[0] = 1.0f / (lv0.x + lv1.x); li[1] = 1.0f / (lv0.y + lv1.y);
    li[2] = 1.0f / (lv0.z + lv1.z); li[3] = 1.0f / (lv0.w + lv1.w);
#pragma unroll
    for (int nb = 0; nb < 4; nb++) {
      const int koff = (bh * 128 + ktb + nb) * 1024 + lane * 8;
      short8x bkr0 = *(const short8x*)(Kr + koff);
      short8x bkr1 = *(const short8x*)(Kr + koff + 512);
      short8x bki0 = *(const short8x*)(Ki + koff);
      short8x bki1 = *(const short8x*)(Ki + koff + 512);
      f32x4 sr = {0.f, 0.f, 0.f, 0.f};
      sr = mfma16(fqr0, bkr0, sr);  sr = mfma16(fqr1, bkr1, sr);
      sr = mfma16(fqi0, bki0, sr);  sr = mfma16(fqi1, bki1, sr);
      f32x4 sa = {0.f, 0.f, 0.f, 0.f};  // Qi.Kr
      sa = mfma16(fqi0, bkr0, sa);  sa = mfma16(fqi1, bkr1, sa);
      f32x4 sb = {0.f, 0.f, 0.f, 0.f};  // Qr.Ki
      sb = mfma16(fqr0, bki0, sb);  sb = mfma16(fqr1, bki1, sb);
#pragma unroll
      for (int r = 0; r < 4; r++) {
        float a = sr[r];
        float d = sa[r] - sb[r];
        float r2 = __builtin_fmaf(a, a, d * d);
        float inv = __builtin_amdgcn_rsqf(r2);
        float arg = inv * __builtin_fmaf(C1F, r2, C2F * a);
        float p = mkf[nb] * __builtin_amdgcn_exp2f(arg) * li[r];
        psum[nb][r] += p;
      }
    }
  }
#pragma unroll
  for (int nb = 0; nb < 4; nb++)
#pragma unroll
    for (int r = 0; r < 4; r++) {
      int qrow = qrow0 + quad * 4 + r;
      out2[((size_t)b * SS + qrow) * SS + kt + nb * 16 + l15] = psum[nb][r] * 0.0625f;
    }
}

extern "C" void kernel_launch(void* const* d_in, const int* in_sizes, int n_in,
                              void* d_out, int out_size, void* d_ws, size_t ws_size,
                              hipStream_t stream) {
  const float* z_real = (const float*)d_in[0];
  const float* z_imag = (const float*)d_in[1];
  const float* Wq_r = (const float*)d_in[2];
  const float* Wq_i = (const float*)d_in[3];
  const float* Wk_r = (const float*)d_in[4];
  const float* Wk_i = (const float*)d_in[5];
  const float* Wv   = (const float*)d_in[6];
  const float* Wo_w = (const float*)d_in[7];
  const float* Wo_b = (const float*)d_in[8];
  const int*   mask = (const int*)d_in[9];
  char* ws = (char*)d_ws;

  // ws layout (bytes). ctxP0/ctxP1 ALIAS WcatT/Xcat: dead after gemm_proj (stream-serial).
  constexpr size_t QKV_BYTES = 8388608;  // B*H*S*DK*2
  unsigned short* Qr   = (unsigned short*)(ws + 0);
  unsigned short* Qi   = (unsigned short*)(ws + QKV_BYTES);
  unsigned short* Kr   = (unsigned short*)(ws + 2 * QKV_BYTES);
  unsigned short* Ki   = (unsigned short*)(ws + 3 * QKV_BYTES);
  unsigned short* VT   = (unsigned short*)(ws + 4 * QKV_BYTES);
  unsigned short* ctx  = (unsigned short*)(ws + 5 * QKV_BYTES);              // 8 MB bf16
  unsigned short* WcatT= (unsigned short*)(ws + 50331648);                   // 20 MB
  unsigned short* WoT  = (unsigned short*)(ws + 71303168);                   // 2 MB
  unsigned short* Xcat = (unsigned short*)(ws + 73400320);                   // 16 MB
  float* ctxP0 = (float*)(ws + 50331648);                                    // aliases WcatT (16 MB)
  float* ctxP1 = (float*)(ws + 73400320);                                    // aliases Xcat (16 MB)
  float* Lp0   = (float*)(ws + 90177536);                                    // 256 KB
  float* Lp1   = (float*)(ws + 90439680);                                    // 256 KB

  float* out  = (float*)d_out;
  float* out2 = out + (size_t)BB * SS * DD;

  pack_w_kernel<<<dim3(45056), dim3(256), 0, stream>>>(Wq_r, Wq_i, Wk_r, Wk_i, Wv, Wo_w, WcatT, WoT);
  pack_x_kernel<<<dim3(32768), dim3(256), 0, stream>>>(z_real, z_imag, Xcat);
  gemm_proj_kernel<<<dim3(32, 40), dim3(256), 0, stream>>>(Xcat, WcatT, Qr, Qi, Kr, Ki, VT);
  flash_kernel<<<dim3(32, 16, 4), dim3(256), 0, stream>>>(Qr, Qi, Kr, Ki, VT, mask, ctxP0, ctxP1, Lp0, Lp1);
  combine_kernel<<<dim3(4096), dim3(256), 0, stream>>>(ctxP0, ctxP1, Lp0, Lp1, ctx);
  gemm_out_kernel<<<dim3(32, 8), dim3(256), 0, stream>>>(ctx, WoT, Wo_b, out);
  probsmean_kernel<<<dim3(32, 32, 2), dim3(256), 0, stream>>>(Qr, Qi, Kr, Ki, mask, Lp0, Lp1, out2);
}